// Round 3
// baseline (714.813 us; speedup 1.0000x reference)
//
#include <hip/hip_runtime.h>
#include <math.h>

// GrapsuleNet forward:
//  K1 k_mean   : xm[b,c] = mean_n x[b,c,n]                       (reads x, 201MB)
//  K2 k_qk     : q = xm@qwT+qb; qk_t[b,c,h] = (1/4)*sum_d q*kw   (kb dropped: softmax-invariant)
//  K3 k_logits : logits[b,h,n] = sum_c x[b,c,n]*qk_t[b,c,h]      (reads x, 201MB; qk in LDS, float2/thread)
//  K4 k_stats  : per (b,h): max m, sum s of exp, pos. NO attn write-back (folded into k_xa).
//  K5 k_xa     : xa partials = attn^T @ x, attn = exp(lg-m)*inv on the fly (reads x, 201MB)
//  K6 k_tail   : per-image fused tail: part-reduce -> values -> msgv -> agg -> mlp -> out.
//                LDS overlaid by phase lifetime: u1 = xa(A-B) / mg+ea(C-D) / h1(E1-E2).
//                Static LDS 57KB (<64KB workgroup limit).
//
// Entire GNN branch is scaled by layer_scale=1e-6 before the residual, so __sinf/__expf
// precision there is irrelevant; the accuracy-critical path is values (f32).

#define Bsz 32
#define Cc  384
#define Nn  4096
#define Ee  256
#define NHh 16
#define HIDh 128

__device__ __forceinline__ float waveSum(float v){
#pragma unroll
  for(int o=32;o;o>>=1) v += __shfl_down(v,(unsigned)o,64);
  return v;
}
__device__ __forceinline__ float waveMax(float v){
#pragma unroll
  for(int o=32;o;o>>=1) v = fmaxf(v, __shfl_down(v,(unsigned)o,64));
  return v;
}
__device__ __forceinline__ float blockSum(float v, float* sm){
  int lane = threadIdx.x & 63, w = threadIdx.x >> 6;
  int nw = blockDim.x >> 6;
  float r = waveSum(v);
  if(lane==0) sm[w] = r;
  __syncthreads();
  float s = 0.f;
  for(int i=0;i<nw;i++) s += sm[i];
  __syncthreads();
  return s;
}
__device__ __forceinline__ float blockMax(float v, float* sm){
  int lane = threadIdx.x & 63, w = threadIdx.x >> 6;
  int nw = blockDim.x >> 6;
  float r = waveMax(v);
  if(lane==0) sm[w] = r;
  __syncthreads();
  float s = -1e30f;
  for(int i=0;i<nw;i++) s = fmaxf(s, sm[i]);
  __syncthreads();
  return s;
}

// ---------------- K1: mean over pixels ----------------
__global__ __launch_bounds__(256) void k_mean(const float* __restrict__ x, float* __restrict__ xm){
  int bc = blockIdx.x, t = threadIdx.x;
  const float4* xr = (const float4*)(x + (size_t)bc*Nn);
  float s = 0.f;
#pragma unroll
  for(int i=0;i<4;i++){ float4 v = xr[t + 256*i]; s += (v.x+v.y) + (v.z+v.w); }
  __shared__ float sm[8];
  s = blockSum(s, sm);
  if(t==0) xm[bc] = s * (1.0f/4096.0f);
}

// ---------------- K2: q and folded qk (coalesced kw reads) ----------------
__global__ __launch_bounds__(384) void k_qk(const float* __restrict__ xm, const float* __restrict__ qw,
                                            const float* __restrict__ qb, const float* __restrict__ kw,
                                            float* __restrict__ qk_t){
  int b = blockIdx.x, t = threadIdx.x;
  __shared__ float xs[Cc];
  __shared__ float qs[Ee];
  if(t < 96) ((float4*)xs)[t] = ((const float4*)(xm + b*Cc))[t];
  __syncthreads();
  if(t < Ee){
    const float4* wr = (const float4*)(qw + (size_t)t*Cc);
    const float4* xv = (const float4*)xs;
    float a = qb[t];
#pragma unroll 4
    for(int c4=0;c4<96;c4++){ float4 w = wr[c4], xx = xv[c4]; a += w.x*xx.x + w.y*xx.y + w.z*xx.z + w.w*xx.w; }
    qs[t] = a;
  }
  __syncthreads();
  int c = t;
#pragma unroll
  for(int hq=0; hq<4; hq++){
    float r0, r1, r2, r3;
#pragma unroll
    for(int hh=0; hh<4; hh++){
      int h = hq*4 + hh;
      float a = 0.f;
#pragma unroll
      for(int d=0; d<16; d++) a += qs[h*16+d] * kw[(size_t)(h*16+d)*Cc + c];
      a *= 0.25f;
      if(hh==0) r0=a; else if(hh==1) r1=a; else if(hh==2) r2=a; else r3=a;
    }
    ((float4*)(qk_t + ((size_t)b*Cc + c)*16))[hq] = make_float4(r0,r1,r2,r3);
  }
}

// ---------------- K3: logits (qk in LDS, 2 n per thread) ----------------
__global__ __launch_bounds__(256) void k_logits(const float* __restrict__ x, const float* __restrict__ qk_t,
                                                float* __restrict__ lg){
  __shared__ float qks[Cc*16];      // 24.6 KB
  int b = blockIdx.y, t = threadIdx.x;
  int n0 = blockIdx.x*512 + t*2;
  {
    const float4* src = (const float4*)(qk_t + (size_t)b*Cc*16);
    float4* dst = (float4*)qks;
#pragma unroll
    for(int i=0;i<6;i++) dst[t + 256*i] = src[t + 256*i];
  }
  __syncthreads();
  float accx[16], accy[16];
#pragma unroll
  for(int h=0;h<16;h++){ accx[h]=0.f; accy[h]=0.f; }
  const float* xb = x + (size_t)b*Cc*Nn + n0;
#pragma unroll 4
  for(int c=0;c<Cc;c++){
    float2 xv = *(const float2*)(xb + (size_t)c*Nn);
    const float4* qv = (const float4*)(qks + c*16);
#pragma unroll
    for(int hq=0;hq<4;hq++){
      float4 q = qv[hq];
      accx[hq*4+0] += xv.x*q.x; accy[hq*4+0] += xv.y*q.x;
      accx[hq*4+1] += xv.x*q.y; accy[hq*4+1] += xv.y*q.y;
      accx[hq*4+2] += xv.x*q.z; accy[hq*4+2] += xv.y*q.z;
      accx[hq*4+3] += xv.x*q.w; accy[hq*4+3] += xv.y*q.w;
    }
  }
#pragma unroll
  for(int h=0;h<16;h++)
    *(float2*)(lg + ((size_t)(b*16+h))*Nn + n0) = make_float2(accx[h], accy[h]);
}

// ---------------- K4: softmax stats (m, 1/s) + pos; no attn write-back ----------------
__global__ __launch_bounds__(256) void k_stats(const float* __restrict__ lg, float* __restrict__ pos,
                                               float* __restrict__ stats){
  int node = blockIdx.x, t = threadIdx.x;
  __shared__ float sm[8];
  const float4* gv = (const float4*)(lg + (size_t)node*Nn);
  float4 vv[4];
  float m = -1e30f;
#pragma unroll
  for(int i=0;i<4;i++){
    vv[i] = gv[t + 256*i];
    m = fmaxf(m, fmaxf(fmaxf(vv[i].x, vv[i].y), fmaxf(vv[i].z, vv[i].w)));
  }
  m = blockMax(m, sm);
  float s = 0.f, px = 0.f, py = 0.f;
#pragma unroll
  for(int i=0;i<4;i++){
    int n0 = 4*(t + 256*i);
    float e0 = __expf(vv[i].x - m), e1 = __expf(vv[i].y - m);
    float e2 = __expf(vv[i].z - m), e3 = __expf(vv[i].w - m);
    float row = (float)(n0 >> 6);
    float c0  = (float)(n0 & 63);
    float es  = (e0+e1)+(e2+e3);
    s  += es;
    px += es * row;
    py += e0*c0 + e1*(c0+1.f) + e2*(c0+2.f) + e3*(c0+3.f);
  }
  s  = blockSum(s,  sm);
  px = blockSum(px, sm);
  py = blockSum(py, sm);
  float inv = 1.0f / s;
  if(t==0){
    pos[node*2]   = px*inv;
    pos[node*2+1] = py*inv;
    stats[node*2]   = m;
    stats[node*2+1] = inv;
  }
}

// ---------------- K5: xa partials = attn^T @ x, attn computed on the fly ----------------
#define XROW 36
__global__ __launch_bounds__(256) void k_xa(const float* __restrict__ x, const float* __restrict__ lg,
                                            const float* __restrict__ stats, float* __restrict__ part){
  __shared__ float xl[Cc*XROW];    // 55.3 KB
  __shared__ float al[NHh*XROW];   // 2.3 KB
  __shared__ float ss[32];
  int b = blockIdx.y, ns = blockIdx.x, t = threadIdx.x;
  int th = t & 3, tc = t >> 2;
  if(t < 32) ss[t] = stats[b*32 + t];
  __syncthreads();
  int ah = t >> 3, aj = t & 7;
  float mA = 0.f, iA = 0.f;
  if(t < 128){ mA = ss[ah*2]; iA = ss[ah*2+1]; }
  float acc[4][6];
#pragma unroll
  for(int k=0;k<4;k++)
#pragma unroll
    for(int m=0;m<6;m++) acc[k][m] = 0.f;

  float4 xr[12];
  float4 ar = make_float4(0,0,0,0);

  auto LOAD = [&](int ch){
    int n0 = ns*256 + ch*32;
    if(t < 128)
      ar = *(const float4*)(lg + ((size_t)(b*16+ah))*Nn + n0 + aj*4);
#pragma unroll
    for(int i=0;i<12;i++){
      int f = t + 256*i;
      int c = f >> 3, j4 = f & 7;
      xr[i] = *(const float4*)(x + ((size_t)(b*Cc+c))*Nn + n0 + j4*4);
    }
  };

  LOAD(0);
  for(int ch=0; ch<8; ch++){
    if(t < 128){
      float4 e;
      e.x = __expf(ar.x - mA)*iA;
      e.y = __expf(ar.y - mA)*iA;
      e.z = __expf(ar.z - mA)*iA;
      e.w = __expf(ar.w - mA)*iA;
      *(float4*)(al + ah*XROW + aj*4) = e;
    }
#pragma unroll
    for(int i=0;i<12;i++){
      int f = t + 256*i;
      int c = f >> 3, j4 = f & 7;
      *(float4*)(xl + c*XROW + j4*4) = xr[i];
    }
    __syncthreads();
    if(ch < 7) LOAD(ch+1);
#pragma unroll
    for(int j4=0;j4<8;j4++){
      float4 a4[4], x4[6];
#pragma unroll
      for(int k=0;k<4;k++) a4[k] = *(const float4*)(al + (th+4*k)*XROW + j4*4);
#pragma unroll
      for(int m=0;m<6;m++) x4[m] = *(const float4*)(xl + (tc+64*m)*XROW + j4*4);
#pragma unroll
      for(int k=0;k<4;k++)
#pragma unroll
        for(int m=0;m<6;m++)
          acc[k][m] += a4[k].x*x4[m].x + a4[k].y*x4[m].y + a4[k].z*x4[m].z + a4[k].w*x4[m].w;
    }
    __syncthreads();
  }
#pragma unroll
  for(int k=0;k<4;k++)
#pragma unroll
    for(int m=0;m<6;m++)
      part[(size_t)ns*(Bsz*NHh*Cc) + (size_t)(b*16 + th + 4*k)*Cc + (tc + 64*m)] = acc[k][m];
}

// ---------------- K6: fused tail, one block per image ----------------
// LDS lifetime overlay (u1, 33KB): xa (A-B) -> mg+ea (C-D) -> h1 (E1-E2).
// vs survives to E2 (residual); ag is read in E1 while h1 is written -> separate.
// Total static LDS: 33.0 + 16.6 + 8.4 + 0.4 = 58.4 KB.
__global__ __launch_bounds__(256) void k_tail(const float* __restrict__ part,
        const float* __restrict__ vw, const float* __restrict__ vb,
        const float* __restrict__ msgw, const float* __restrict__ msgb,
        const float* __restrict__ pos, const float* __restrict__ brff,
        const float* __restrict__ embw,
        const float* __restrict__ l1w, const float* __restrict__ l1b,
        const float* __restrict__ l2w, const float* __restrict__ l2b,
        const float* __restrict__ ls, float* __restrict__ out){
  __shared__ float u1[16*516];   // 33.0 KB union
  __shared__ float vs[16*260];   // 16.6 KB
  __shared__ float ag[16*132];   //  8.4 KB
  __shared__ float ps[32];
  __shared__ float bfs[64];
  float* xa = u1;                // stride 388, 6208 floats (phases A-B)
  float* mg = u1;                // stride 132, 2112 floats (phases C-D)
  float* ea = u1 + 2112;         // stride 68, 1088 floats (phase D); 16B-aligned
  float* h1 = u1;                // stride 516, 8256 floats (phases E1-E2)
  int b = blockIdx.x, t = threadIdx.x;
  int w = t >> 6, lane = t & 63;

  // ---- phase A: xa[j][c] = sum_p part[p][(b,j)][c] ----
#pragma unroll
  for(int i=0;i<6;i++){
    int idx = t + 256*i;            // 0..1535 = 16 j * 96 c4
    int j = idx / 96, c4 = idx % 96;
    float4 s = make_float4(0,0,0,0);
    const float* base = part + (size_t)(b*16+j)*Cc + c4*4;
#pragma unroll
    for(int p=0;p<16;p++){
      float4 v = *(const float4*)(base + (size_t)p*(Bsz*NHh*Cc));
      s.x+=v.x; s.y+=v.y; s.z+=v.z; s.w+=v.w;
    }
    *(float4*)(xa + j*388 + c4*4) = s;
  }
  if(t < 32) ps[t] = pos[b*32 + t];
  if(t < 64) bfs[t] = brff[t];
  __syncthreads();

  // ---- phase B: values: vs[j][e] = vb[e] + xa[j] . vw[e] ----
  {
    float acc[4][4];
#pragma unroll
    for(int jj=0;jj<4;jj++)
#pragma unroll
      for(int ee=0;ee<4;ee++) acc[jj][ee] = 0.f;
    for(int c4=0;c4<96;c4++){
      float4 w4[4], a4[4];
#pragma unroll
      for(int ee=0;ee<4;ee++) w4[ee] = *(const float4*)(vw + (size_t)(lane+64*ee)*Cc + c4*4);
#pragma unroll
      for(int jj=0;jj<4;jj++) a4[jj] = *(const float4*)(xa + (w*4+jj)*388 + c4*4);
#pragma unroll
      for(int jj=0;jj<4;jj++)
#pragma unroll
        for(int ee=0;ee<4;ee++)
          acc[jj][ee] += a4[jj].x*w4[ee].x + a4[jj].y*w4[ee].y + a4[jj].z*w4[ee].z + a4[jj].w*w4[ee].w;
    }
    __syncthreads();               // xa reads done before mg overwrites u1
#pragma unroll
    for(int jj=0;jj<4;jj++)
#pragma unroll
      for(int ee=0;ee<4;ee++)
        vs[(w*4+jj)*260 + lane+64*ee] = acc[jj][ee] + vb[lane+64*ee];
  }
  __syncthreads();

  // ---- phase C: msgv: mg[j][h] = msgb[h] + vs[j] . msgw[h] ----
  {
    float acc[4][2];
#pragma unroll
    for(int jj=0;jj<4;jj++){ acc[jj][0]=0.f; acc[jj][1]=0.f; }
    for(int e4=0;e4<64;e4++){
      float4 w4[2], v4[4];
#pragma unroll
      for(int hh=0;hh<2;hh++) w4[hh] = *(const float4*)(msgw + (size_t)(lane+64*hh)*Ee + e4*4);
#pragma unroll
      for(int jj=0;jj<4;jj++) v4[jj] = *(const float4*)(vs + (w*4+jj)*260 + e4*4);
#pragma unroll
      for(int jj=0;jj<4;jj++)
#pragma unroll
        for(int hh=0;hh<2;hh++)
          acc[jj][hh] += v4[jj].x*w4[hh].x + v4[jj].y*w4[hh].y + v4[jj].z*w4[hh].z + v4[jj].w*w4[hh].w;
    }
#pragma unroll
    for(int jj=0;jj<4;jj++)
#pragma unroll
      for(int hh=0;hh<2;hh++)
        mg[(w*4+jj)*132 + lane+64*hh] = acc[jj][hh] + msgb[lane+64*hh];
  }
  __syncthreads();

  // ---- phase D: agg: ag[j][h] = (1/15) sum_{i!=j} mg[i][h] * (ea(i->j) . embw[h]) ----
  {
    int h = t & 127;
    int jbase = (t >> 7) * 8;     // t<128 -> j 0..7, t>=128 -> j 8..15
    float4 er[16];
#pragma unroll
    for(int k=0;k<16;k++) er[k] = *(const float4*)(embw + (size_t)h*64 + k*4);
    float accJ[8];
#pragma unroll
    for(int jl=0;jl<8;jl++) accJ[jl] = 0.f;
    for(int i=0;i<16;i++){
      __syncthreads();            // previous iter's ea readers done
      {                           // ea(src=i, dst=j): thread j=t>>4, k=(t&15)*2..+1
        int j = t >> 4, kk = (t & 15)*2;
        float rx = ps[2*i]   - ps[2*j];
        float ry = ps[2*i+1] - ps[2*j+1];
#pragma unroll
        for(int u=0;u<2;u++){
          int k = kk + u;
          float pr = rx*bfs[2*k] + ry*bfs[2*k+1];
          ea[j*68 + k]      = 1.41421356f * __sinf(pr);
          ea[j*68 + 32 + k] = 1.41421356f * __cosf(pr);
        }
      }
      __syncthreads();
      float mvh = mg[i*132 + h];
#pragma unroll
      for(int jl=0;jl<8;jl++){
        int j = jbase + jl;
        if(j == i) continue;      // wave-uniform branch
        float psi = 0.f;
        const float4* ev = (const float4*)(ea + j*68);
#pragma unroll
        for(int k=0;k<16;k++){ float4 e4 = ev[k]; psi += e4.x*er[k].x + e4.y*er[k].y + e4.z*er[k].z + e4.w*er[k].w; }
        accJ[jl] += mvh * psi;
      }
    }
    __syncthreads();              // mg/ea reads done before h1 overwrites u1
#pragma unroll
    for(int jl=0;jl<8;jl++) ag[(jbase+jl)*132 + h] = accJ[jl] * (1.0f/15.0f);
  }
  __syncthreads();

  // ---- phase E1: h1[j][u] = silu(l1b[u] + ag[j] . l1w[u]) ----
  {
    float acc[4][8];
#pragma unroll
    for(int jj=0;jj<4;jj++)
#pragma unroll
      for(int uu=0;uu<8;uu++) acc[jj][uu] = 0.f;
    for(int c4=0;c4<32;c4++){
      float4 w4[8], a4[4];
#pragma unroll
      for(int uu=0;uu<8;uu++) w4[uu] = *(const float4*)(l1w + (size_t)(lane+64*uu)*HIDh + c4*4);
#pragma unroll
      for(int jj=0;jj<4;jj++) a4[jj] = *(const float4*)(ag + (w*4+jj)*132 + c4*4);
#pragma unroll
      for(int jj=0;jj<4;jj++)
#pragma unroll
        for(int uu=0;uu<8;uu++)
          acc[jj][uu] += a4[jj].x*w4[uu].x + a4[jj].y*w4[uu].y + a4[jj].z*w4[uu].z + a4[jj].w*w4[uu].w;
    }
#pragma unroll
    for(int jj=0;jj<4;jj++)
#pragma unroll
      for(int uu=0;uu<8;uu++){
        float a = acc[jj][uu] + l1b[lane+64*uu];
        h1[(w*4+jj)*516 + lane+64*uu] = a / (1.0f + __expf(-a));
      }
  }
  __syncthreads();

  // ---- phase E2: o[j][e] = l2b[e] + h1[j] . l2w[e]; out = ls*o + values ----
  {
    float acc[4][4];
#pragma unroll
    for(int jj=0;jj<4;jj++)
#pragma unroll
      for(int ee=0;ee<4;ee++) acc[jj][ee] = 0.f;
    for(int u4=0;u4<128;u4++){
      float4 w4[4], hv[4];
#pragma unroll
      for(int ee=0;ee<4;ee++) w4[ee] = *(const float4*)(l2w + (size_t)(lane+64*ee)*512 + u4*4);
#pragma unroll
      for(int jj=0;jj<4;jj++) hv[jj] = *(const float4*)(h1 + (w*4+jj)*516 + u4*4);
#pragma unroll
      for(int jj=0;jj<4;jj++)
#pragma unroll
        for(int ee=0;ee<4;ee++)
          acc[jj][ee] += hv[jj].x*w4[ee].x + hv[jj].y*w4[ee].y + hv[jj].z*w4[ee].z + hv[jj].w*w4[ee].w;
    }
#pragma unroll
    for(int jj=0;jj<4;jj++)
#pragma unroll
      for(int ee=0;ee<4;ee++){
        int e = lane + 64*ee;
        size_t oi = (size_t)(b*16 + w*4+jj)*Ee + e;
        out[oi] = ls[e]*(acc[jj][ee] + l2b[e]) + vs[(w*4+jj)*260 + e];
      }
  }
}

extern "C" void kernel_launch(void* const* d_in, const int* in_sizes, int n_in,
                              void* d_out, int out_size, void* d_ws, size_t ws_size,
                              hipStream_t stream) {
  const float* x    = (const float*)d_in[0];
  const float* qw   = (const float*)d_in[1];
  const float* qb   = (const float*)d_in[2];
  const float* kw   = (const float*)d_in[3];
  // d_in[4] = kb: adds a per-(b,h) constant to logits -> cancels in softmax; unused.
  const float* vw   = (const float*)d_in[5];
  const float* vb   = (const float*)d_in[6];
  const float* brff = (const float*)d_in[7];
  const float* msgw = (const float*)d_in[8];
  const float* msgb = (const float*)d_in[9];
  const float* embw = (const float*)d_in[10];
  const float* l1w  = (const float*)d_in[11];
  const float* l1b  = (const float*)d_in[12];
  const float* l2w  = (const float*)d_in[13];
  const float* l2b  = (const float*)d_in[14];
  const float* lsc  = (const float*)d_in[15];
  // d_in[16], d_in[17] = edge_src/edge_dst: deterministic fully-connected graph; handled structurally.

  float* W      = (float*)d_ws;
  float* xm     = W;                    // 12288
  float* qkt    = xm  + 12288;          // 196608
  float* lg     = qkt + 196608;         // 2097152 (raw logits; never normalized in memory)
  float* pos    = lg  + 2097152;        // 1024
  float* stats  = pos + 1024;           // 1024  (m, 1/s per node)
  float* part   = stats + 1024;         // 16*196608 = 3145728
  float* out    = (float*)d_out;

  k_mean  <<<Bsz*Cc, 256, 0, stream>>>(x, xm);
  k_qk    <<<Bsz, 384, 0, stream>>>(xm, qw, qb, kw, qkt);
  k_logits<<<dim3(8, Bsz), 256, 0, stream>>>(x, qkt, lg);
  k_stats <<<Bsz*NHh, 256, 0, stream>>>(lg, pos, stats);
  k_xa    <<<dim3(16, Bsz), 256, 0, stream>>>(x, lg, stats, part);
  k_tail  <<<Bsz, 256, 0, stream>>>(part, vw, vb, msgw, msgb, pos, brff, embw,
                                    l1w, l1b, l2w, l2b, lsc, out);
}

// Round 4
// 564.872 us; speedup vs baseline: 1.2654x; 1.2654x over previous
//
#include <hip/hip_runtime.h>
#include <math.h>

// GrapsuleNet forward:
//  K1 k_mean   : xm[b,c] = mean_n x[b,c,n]                        (reads x, 201MB)
//  K2 k_qk     : q = xm@qwT+qb; qk_t[b,c,h] = (1/4)*sum_d q*kw    (kb dropped: softmax-invariant)
//  K3 k_logits : logits[b,h,n] = sum_c x[b,c,n]*qk_t[b,c,h]       (reads x, 201MB)
//                + per-block softmax partials (m, s, px, py) -> spart  [k_stats eliminated]
//  K4 k_xa     : flash-merge partials -> (m, 1/s) + pos; xa partials = attn^T @ x
//                with attn = exp(lg-m)*inv on the fly             (reads x, 201MB)
//  K5 k_values : xa = sum 16 partials; values = xa@vwT+vb; msgv = values@msg_wT+msg_b (512 blocks)
//  K6 k_agg    : per-dst aggregation over the 15 in-neighbors     (512 blocks)
//  K7 k_mlp    : silu MLP + layer_scale*o + values -> out         (512 blocks)
//
// R3 lesson: per-image tail fusion (32 blocks) = 1.5% occupancy, 227us. Tail stays 512-block.
// Entire GNN branch is scaled by layer_scale=1e-6 before the residual, so __sinf/__expf
// precision there is irrelevant; the accuracy-critical path is values (f32).

#define Bsz 32
#define Cc  384
#define Nn  4096
#define Ee  256
#define NHh 16
#define HIDh 128

__device__ __forceinline__ float waveSum(float v){
#pragma unroll
  for(int o=32;o;o>>=1) v += __shfl_down(v,(unsigned)o,64);
  return v;
}
__device__ __forceinline__ float waveMaxAll(float v){
#pragma unroll
  for(int o=1;o<64;o<<=1) v = fmaxf(v, __shfl_xor(v,(unsigned)o,64));
  return v;
}
__device__ __forceinline__ float waveSumAll(float v){
#pragma unroll
  for(int o=1;o<64;o<<=1) v += __shfl_xor(v,(unsigned)o,64);
  return v;
}
__device__ __forceinline__ float blockSum(float v, float* sm){
  int lane = threadIdx.x & 63, w = threadIdx.x >> 6;
  int nw = blockDim.x >> 6;
  float r = waveSum(v);
  if(lane==0) sm[w] = r;
  __syncthreads();
  float s = 0.f;
  for(int i=0;i<nw;i++) s += sm[i];
  __syncthreads();
  return s;
}

// ---------------- K1: mean over pixels ----------------
__global__ __launch_bounds__(256) void k_mean(const float* __restrict__ x, float* __restrict__ xm){
  int bc = blockIdx.x, t = threadIdx.x;
  const float4* xr = (const float4*)(x + (size_t)bc*Nn);
  float s = 0.f;
#pragma unroll
  for(int i=0;i<4;i++){ float4 v = xr[t + 256*i]; s += (v.x+v.y) + (v.z+v.w); }
  __shared__ float sm[8];
  s = blockSum(s, sm);
  if(t==0) xm[bc] = s * (1.0f/4096.0f);
}

// ---------------- K2: q and folded qk (coalesced kw reads) ----------------
__global__ __launch_bounds__(384) void k_qk(const float* __restrict__ xm, const float* __restrict__ qw,
                                            const float* __restrict__ qb, const float* __restrict__ kw,
                                            float* __restrict__ qk_t){
  int b = blockIdx.x, t = threadIdx.x;
  __shared__ float xs[Cc];
  __shared__ float qs[Ee];
  if(t < 96) ((float4*)xs)[t] = ((const float4*)(xm + b*Cc))[t];
  __syncthreads();
  if(t < Ee){
    const float4* wr = (const float4*)(qw + (size_t)t*Cc);
    const float4* xv = (const float4*)xs;
    float a = qb[t];
#pragma unroll 4
    for(int c4=0;c4<96;c4++){ float4 w = wr[c4], xx = xv[c4]; a += w.x*xx.x + w.y*xx.y + w.z*xx.z + w.w*xx.w; }
    qs[t] = a;
  }
  __syncthreads();
  int c = t;
#pragma unroll
  for(int hq=0; hq<4; hq++){
    float r0, r1, r2, r3;
#pragma unroll
    for(int hh=0; hh<4; hh++){
      int h = hq*4 + hh;
      float a = 0.f;
#pragma unroll
      for(int d=0; d<16; d++) a += qs[h*16+d] * kw[(size_t)(h*16+d)*Cc + c];
      a *= 0.25f;
      if(hh==0) r0=a; else if(hh==1) r1=a; else if(hh==2) r2=a; else r3=a;
    }
    ((float4*)(qk_t + ((size_t)b*Cc + c)*16))[hq] = make_float4(r0,r1,r2,r3);
  }
}

// ---------------- K3: logits + per-block softmax partials ----------------
// grid (16, Bsz) = 512 blocks (2/CU), 1 n per thread, unroll 8.
// After the main loop, block reduces its 256 logits per h into (m, sum_e, px, py)
// partials: spart[(b*16+h)*16 + ns] = float4(m, s, px, py).
__global__ __launch_bounds__(256) void k_logits(const float* __restrict__ x, const float* __restrict__ qk_t,
                                                float* __restrict__ lg, float* __restrict__ spart){
  __shared__ float qks[Cc*16];      // 24.6 KB; reused as sl[16][256] for the stats phase
  int b = blockIdx.y, ns = blockIdx.x, t = threadIdx.x;
  int n = ns*256 + t;
  {
    const float4* src = (const float4*)(qk_t + (size_t)b*Cc*16);
    float4* dst = (float4*)qks;
#pragma unroll
    for(int i=0;i<6;i++) dst[t + 256*i] = src[t + 256*i];
  }
  __syncthreads();
  float acc[16];
#pragma unroll
  for(int h=0;h<16;h++) acc[h] = 0.f;
  const float* xb = x + (size_t)b*Cc*Nn + n;
#pragma unroll 8
  for(int c=0;c<Cc;c++){
    float xv = xb[(size_t)c*Nn];               // coalesced, streamed once
    const float4* qv = (const float4*)(qks + c*16);  // wave-uniform -> LDS broadcast
    float4 q0 = qv[0], q1 = qv[1], q2 = qv[2], q3 = qv[3];
    acc[0]  += xv*q0.x; acc[1]  += xv*q0.y; acc[2]  += xv*q0.z; acc[3]  += xv*q0.w;
    acc[4]  += xv*q1.x; acc[5]  += xv*q1.y; acc[6]  += xv*q1.z; acc[7]  += xv*q1.w;
    acc[8]  += xv*q2.x; acc[9]  += xv*q2.y; acc[10] += xv*q2.z; acc[11] += xv*q2.w;
    acc[12] += xv*q3.x; acc[13] += xv*q3.y; acc[14] += xv*q3.z; acc[15] += xv*q3.w;
  }
#pragma unroll
  for(int h=0;h<16;h++) lg[((size_t)(b*16+h))*Nn + n] = acc[h];

  // ---- stats partials: transpose through LDS, wave w reduces h = w*4..w*4+3 ----
  __syncthreads();                   // all qks reads done; safe to overwrite
  float* sl = qks;                   // [16][256]
#pragma unroll
  for(int h=0;h<16;h++) sl[h*256 + t] = acc[h];
  __syncthreads();
  int w = t >> 6, lane = t & 63;
#pragma unroll
  for(int hh=0; hh<4; hh++){
    int h = w*4 + hh;
    float v0 = sl[h*256 + lane], v1 = sl[h*256 + 64 + lane];
    float v2 = sl[h*256 + 128 + lane], v3 = sl[h*256 + 192 + lane];
    float m = waveMaxAll(fmaxf(fmaxf(v0,v1), fmaxf(v2,v3)));
    float e0 = __expf(v0-m), e1 = __expf(v1-m), e2 = __expf(v2-m), e3 = __expf(v3-m);
    // n = ns*256 + quarter*64 + lane -> row = n>>6 = ns*4+quarter, col = n&63 = lane
    float row0 = (float)(ns*4);
    float col  = (float)lane;
    float s  = (e0+e1)+(e2+e3);
    float px = e0*row0 + e1*(row0+1.f) + e2*(row0+2.f) + e3*(row0+3.f);
    float py = s * col;
    float s_t  = waveSumAll(s);
    float px_t = waveSumAll(px);
    float py_t = waveSumAll(py);
    if(lane==0)
      *(float4*)(spart + ((size_t)(b*16+h)*16 + ns)*4) = make_float4(m, s_t, px_t, py_t);
  }
}

// ---------------- K4: xa partials = attn^T @ x, attn computed on the fly ----------------
// Prologue: flash-merge the 16 per-block partials -> (m, 1/s); ns==0 writes pos.
#define XROW 36
__global__ __launch_bounds__(256) void k_xa(const float* __restrict__ x, const float* __restrict__ lg,
                                            const float* __restrict__ spart, float* __restrict__ pos,
                                            float* __restrict__ part){
  __shared__ float xl[Cc*XROW];    // 55.3 KB
  __shared__ float al[NHh*XROW];   // 2.3 KB
  __shared__ float ss[32];
  int b = blockIdx.y, ns = blockIdx.x, t = threadIdx.x;
  int th = t & 3, tc = t >> 2;
  if(t < 64){                      // wave 0: 4 lanes per h merge 16 partials
    int h = t >> 2, qq = t & 3;
    const float4* sp = (const float4*)spart + (size_t)(b*16+h)*16 + qq*4;
    float4 p0 = sp[0], p1 = sp[1], p2 = sp[2], p3 = sp[3];
    float m = fmaxf(fmaxf(p0.x,p1.x), fmaxf(p2.x,p3.x));
    m = fmaxf(m, __shfl_xor(m, 1u, 64));
    m = fmaxf(m, __shfl_xor(m, 2u, 64));
    float w0 = __expf(p0.x-m), w1 = __expf(p1.x-m), w2 = __expf(p2.x-m), w3 = __expf(p3.x-m);
    float s  = p0.y*w0 + p1.y*w1 + p2.y*w2 + p3.y*w3;
    float px = p0.z*w0 + p1.z*w1 + p2.z*w2 + p3.z*w3;
    float py = p0.w*w0 + p1.w*w1 + p2.w*w2 + p3.w*w3;
    s  += __shfl_xor(s, 1u, 64);  s  += __shfl_xor(s, 2u, 64);
    px += __shfl_xor(px,1u, 64);  px += __shfl_xor(px,2u, 64);
    py += __shfl_xor(py,1u, 64);  py += __shfl_xor(py,2u, 64);
    if(qq==0){
      float inv = 1.0f/s;
      ss[h*2] = m; ss[h*2+1] = inv;
      if(ns==0){ pos[(b*16+h)*2] = px*inv; pos[(b*16+h)*2+1] = py*inv; }
    }
  }
  __syncthreads();
  int ah = t >> 3, aj = t & 7;
  float mA = 0.f, iA = 0.f;
  if(t < 128){ mA = ss[ah*2]; iA = ss[ah*2+1]; }
  float acc[4][6];
#pragma unroll
  for(int k=0;k<4;k++)
#pragma unroll
    for(int m=0;m<6;m++) acc[k][m] = 0.f;

  float4 xr[12];
  float4 ar = make_float4(0,0,0,0);

  auto LOAD = [&](int ch){
    int n0 = ns*256 + ch*32;
    if(t < 128)
      ar = *(const float4*)(lg + ((size_t)(b*16+ah))*Nn + n0 + aj*4);
#pragma unroll
    for(int i=0;i<12;i++){
      int f = t + 256*i;
      int c = f >> 3, j4 = f & 7;
      xr[i] = *(const float4*)(x + ((size_t)(b*Cc+c))*Nn + n0 + j4*4);
    }
  };

  LOAD(0);
  for(int ch=0; ch<8; ch++){
    if(t < 128){
      float4 e;
      e.x = __expf(ar.x - mA)*iA;
      e.y = __expf(ar.y - mA)*iA;
      e.z = __expf(ar.z - mA)*iA;
      e.w = __expf(ar.w - mA)*iA;
      *(float4*)(al + ah*XROW + aj*4) = e;
    }
#pragma unroll
    for(int i=0;i<12;i++){
      int f = t + 256*i;
      int c = f >> 3, j4 = f & 7;
      *(float4*)(xl + c*XROW + j4*4) = xr[i];
    }
    __syncthreads();
    if(ch < 7) LOAD(ch+1);
#pragma unroll
    for(int j4=0;j4<8;j4++){
      float4 a4[4], x4[6];
#pragma unroll
      for(int k=0;k<4;k++) a4[k] = *(const float4*)(al + (th+4*k)*XROW + j4*4);
#pragma unroll
      for(int m=0;m<6;m++) x4[m] = *(const float4*)(xl + (tc+64*m)*XROW + j4*4);
#pragma unroll
      for(int k=0;k<4;k++)
#pragma unroll
        for(int m=0;m<6;m++)
          acc[k][m] += a4[k].x*x4[m].x + a4[k].y*x4[m].y + a4[k].z*x4[m].z + a4[k].w*x4[m].w;
    }
    __syncthreads();
  }
#pragma unroll
  for(int k=0;k<4;k++)
#pragma unroll
    for(int m=0;m<6;m++)
      part[(size_t)ns*(Bsz*NHh*Cc) + (size_t)(b*16 + th + 4*k)*Cc + (tc + 64*m)] = acc[k][m];
}

// ---------------- K5: xa reduce (16 partials) + values + msgv ----------------
__global__ __launch_bounds__(256) void k_values(const float* __restrict__ part, const float* __restrict__ vw,
                                                const float* __restrict__ vb, const float* __restrict__ msg_w,
                                                const float* __restrict__ msg_b,
                                                float* __restrict__ values, float* __restrict__ msgv){
  int node = blockIdx.x, t = threadIdx.x;
  __shared__ float xa[Cc];
  __shared__ float vs[Ee];
  if(t < 96){
    float4 s = make_float4(0,0,0,0);
#pragma unroll
    for(int p=0;p<16;p++){
      float4 v = *(const float4*)(part + (size_t)p*(Bsz*NHh*Cc) + (size_t)node*Cc + t*4);
      s.x += v.x; s.y += v.y; s.z += v.z; s.w += v.w;
    }
    *(float4*)(xa + t*4) = s;
  }
  __syncthreads();
  {
    const float4* wr = (const float4*)(vw + (size_t)t*Cc);
    const float4* xv = (const float4*)xa;
    float a = vb[t];
#pragma unroll 4
    for(int c4=0;c4<96;c4++){ float4 w = wr[c4], xx = xv[c4]; a += w.x*xx.x + w.y*xx.y + w.z*xx.z + w.w*xx.w; }
    values[(size_t)node*Ee + t] = a;
    vs[t] = a;
  }
  __syncthreads();
  if(t < HIDh){
    const float4* mr = (const float4*)(msg_w + (size_t)t*Ee);
    const float4* vv = (const float4*)vs;
    float a = msg_b[t];
#pragma unroll 4
    for(int e4=0;e4<64;e4++){ float4 w = mr[e4], xx = vv[e4]; a += w.x*xx.x + w.y*xx.y + w.z*xx.z + w.w*xx.w; }
    msgv[(size_t)node*HIDh + t] = a;
  }
}

// ---------------- K6: graph aggregation (mean over 15 in-neighbors) ----------------
__global__ __launch_bounds__(128) void k_agg(const float* __restrict__ pos, const float* __restrict__ msgv,
                                             const float* __restrict__ brff, const float* __restrict__ emb_w,
                                             float* __restrict__ agg){
  int node = blockIdx.x, t = threadIdx.x;
  int b = node >> 4, jj = node & 15;
  __shared__ float ps[32];
  __shared__ float bf[64];
  __shared__ float mv[16*HIDh];
  __shared__ float ea[64];
  if(t < 32) ps[t] = pos[b*32 + t];
  if(t < 64) bf[t] = brff[t];
#pragma unroll
  for(int i=0;i<4;i++){ int f = t + 128*i; ((float4*)mv)[f] = ((const float4*)(msgv + (size_t)b*16*HIDh))[f]; }
  float4 er[16];
#pragma unroll
  for(int i=0;i<16;i++) er[i] = ((const float4*)(emb_w + (size_t)t*64))[i];
  __syncthreads();
  float pxj = ps[jj*2], pyj = ps[jj*2+1];
  float acc = 0.f;
  for(int i=0;i<16;i++){
    if(i == jj) continue;            // jj is block-uniform: barriers stay aligned
    float rx = ps[i*2]   - pxj;
    float ry = ps[i*2+1] - pyj;
    __syncthreads();
    if(t < 32){
      float pr = rx*bf[t*2] + ry*bf[t*2+1];
      ea[t]    = 1.41421356f * __sinf(pr);
      ea[t+32] = 1.41421356f * __cosf(pr);
    }
    __syncthreads();
    float psi = 0.f;
    const float4* eav = (const float4*)ea;
#pragma unroll
    for(int k=0;k<16;k++){ float4 e4 = eav[k]; psi += e4.x*er[k].x + e4.y*er[k].y + e4.z*er[k].z + e4.w*er[k].w; }
    acc += mv[i*HIDh + t] * psi;
  }
  agg[(size_t)node*HIDh + t] = acc * (1.0f/15.0f);
}

// ---------------- K7: MLP + layer scale + residual ----------------
__global__ __launch_bounds__(256) void k_mlp(const float* __restrict__ agg, const float* __restrict__ l1w,
                                             const float* __restrict__ l1b, const float* __restrict__ l2w,
                                             const float* __restrict__ l2b, const float* __restrict__ ls,
                                             const float* __restrict__ values, float* __restrict__ out){
  int node = blockIdx.x, t = threadIdx.x;
  __shared__ float ag[HIDh];
  __shared__ float h1[512];
  if(t < 32) ((float4*)ag)[t] = ((const float4*)(agg + (size_t)node*HIDh))[t];
  __syncthreads();
#pragma unroll
  for(int r=0;r<2;r++){
    int u = t + r*256;
    const float4* wr = (const float4*)(l1w + (size_t)u*HIDh);
    const float4* av = (const float4*)ag;
    float a = l1b[u];
#pragma unroll 4
    for(int k=0;k<32;k++){ float4 w = wr[k], xx = av[k]; a += w.x*xx.x + w.y*xx.y + w.z*xx.z + w.w*xx.w; }
    h1[u] = a / (1.0f + __expf(-a));   // silu
  }
  __syncthreads();
  {
    const float4* wr = (const float4*)(l2w + (size_t)t*512);
    const float4* hv = (const float4*)h1;
    float o = l2b[t];
#pragma unroll 4
    for(int k=0;k<128;k++){ float4 w = wr[k], xx = hv[k]; o += w.x*xx.x + w.y*xx.y + w.z*xx.z + w.w*xx.w; }
    size_t oi = (size_t)node*Ee + t;
    out[oi] = ls[t]*o + values[oi];
  }
}

extern "C" void kernel_launch(void* const* d_in, const int* in_sizes, int n_in,
                              void* d_out, int out_size, void* d_ws, size_t ws_size,
                              hipStream_t stream) {
  const float* x    = (const float*)d_in[0];
  const float* qw   = (const float*)d_in[1];
  const float* qb   = (const float*)d_in[2];
  const float* kw   = (const float*)d_in[3];
  // d_in[4] = kb: adds a per-(b,h) constant to logits -> cancels in softmax; unused.
  const float* vw   = (const float*)d_in[5];
  const float* vb   = (const float*)d_in[6];
  const float* brff = (const float*)d_in[7];
  const float* msgw = (const float*)d_in[8];
  const float* msgb = (const float*)d_in[9];
  const float* embw = (const float*)d_in[10];
  const float* l1w  = (const float*)d_in[11];
  const float* l1b  = (const float*)d_in[12];
  const float* l2w  = (const float*)d_in[13];
  const float* l2b  = (const float*)d_in[14];
  const float* lsc  = (const float*)d_in[15];
  // d_in[16], d_in[17] = edge_src/edge_dst: deterministic fully-connected graph; handled structurally.

  float* W      = (float*)d_ws;
  float* xm     = W;                    // 12288
  float* qkt    = xm  + 12288;          // 196608
  float* lg     = qkt + 196608;         // 2097152 (raw logits; never normalized in memory)
  float* pos    = lg  + 2097152;        // 1024
  float* spart  = pos + 1024;           // 512 nodes * 16 blocks * 4 = 32768
  float* part   = spart + 32768;        // 16*196608 = 3145728
  float* values = part + 3145728;       // 131072
  float* msgv   = values + 131072;      // 65536
  float* agg    = msgv + 65536;         // 65536  (total ~22 MiB)
  float* out    = (float*)d_out;

  k_mean  <<<Bsz*Cc, 256, 0, stream>>>(x, xm);
  k_qk    <<<Bsz, 384, 0, stream>>>(xm, qw, qb, kw, qkt);
  k_logits<<<dim3(16, Bsz), 256, 0, stream>>>(x, qkt, lg, spart);
  k_xa    <<<dim3(16, Bsz), 256, 0, stream>>>(x, lg, spart, pos, part);
  k_values<<<Bsz*NHh, 256, 0, stream>>>(part, vw, vb, msgw, msgb, values, msgv);
  k_agg   <<<Bsz*NHh, 128, 0, stream>>>(pos, msgv, brff, embw, agg);
  k_mlp   <<<Bsz*NHh, 256, 0, stream>>>(agg, l1w, l1b, l2w, l2b, lsc, values, out);
}